// Round 4
// baseline (224.936 us; speedup 1.0000x reference)
//
#include <hip/hip_runtime.h>
#include <hip/hip_bf16.h>

typedef __bf16 bf16x8 __attribute__((ext_vector_type(8)));
typedef float f32x4 __attribute__((ext_vector_type(4)));
typedef unsigned short u16x8 __attribute__((ext_vector_type(8)));
typedef unsigned short u16x4 __attribute__((ext_vector_type(4)));

// B=128, T=256, D=512, H=8, HD=64. M = B*T = 32768.

__device__ __forceinline__ unsigned short f2bf(float f) {
  unsigned u = __float_as_uint(f);
  u += 0x7fffu + ((u >> 16) & 1u);   // RNE
  return (unsigned short)(u >> 16);
}

// async global->LDS, 16B per lane. LDS dest wave-uniform; HW adds lane*16.
__device__ __forceinline__ void async16(const void* g, void* l) {
  __builtin_amdgcn_global_load_lds(
      (const __attribute__((address_space(1))) void*)g,
      (__attribute__((address_space(3))) void*)l, 16, 0, 0);
}

// ---------------- x fp32 -> bf16 ----------------
__global__ __launch_bounds__(256) void k_convert_x(const float* __restrict__ in,
                                                   unsigned short* __restrict__ out) {
  int i = blockIdx.x * 256 + threadIdx.x;
  const float4* p = (const float4*)in + (size_t)i * 2;
  float4 a = p[0], b = p[1];
  u16x8 o;
  o[0] = f2bf(a.x); o[1] = f2bf(a.y); o[2] = f2bf(a.z); o[3] = f2bf(a.w);
  o[4] = f2bf(b.x); o[5] = f2bf(b.y); o[6] = f2bf(b.z); o[7] = f2bf(b.w);
  *((u16x8*)out + i) = o;
}

// ---------------- W fp32 [batch][rows][cols] -> bf16 [batch][cols][rows] ----------------
__global__ __launch_bounds__(256) void k_transpose_w(const float* __restrict__ in,
                                                     unsigned short* __restrict__ out,
                                                     int rows, int cols) {
  __shared__ unsigned short tile[64][72];
  int c0 = blockIdx.x * 64, r0 = blockIdx.y * 64;
  const float* inb = in + (size_t)blockIdx.z * rows * cols;
  unsigned short* outb = out + (size_t)blockIdx.z * rows * cols;
  int tid = threadIdx.x;
  int r = tid >> 2, cq = (tid & 3) * 16;
  const float* src = inb + (size_t)(r0 + r) * cols + c0 + cq;
#pragma unroll
  for (int i = 0; i < 16; i += 4) {
    float4 v = *(const float4*)(src + i);
    tile[r][cq + i + 0] = f2bf(v.x);
    tile[r][cq + i + 1] = f2bf(v.y);
    tile[r][cq + i + 2] = f2bf(v.z);
    tile[r][cq + i + 3] = f2bf(v.w);
  }
  __syncthreads();
  int cr = tid >> 2, rq = (tid & 3) * 16;
  u16x8 o0, o1;
#pragma unroll
  for (int i = 0; i < 8; ++i) o0[i] = tile[rq + i][cr];
#pragma unroll
  for (int i = 0; i < 8; ++i) o1[i] = tile[rq + 8 + i][cr];
  unsigned short* dst = outb + (size_t)(c0 + cr) * rows + r0 + rq;
  *(u16x8*)dst = o0;
  *(u16x8*)(dst + 8) = o1;
}

// ---------------- 256x256x(K=512) 8-phase GEMM, C = A * Bmat^T ----------------
// 8 waves (2M x 4N), BK=64, 128 KiB LDS double-buffer, T2 swizzle, counted vmcnt.
// __launch_bounds__(512,1): 256-VGPR budget. (512,2) capped at 128 and spilled
// the 128-VGPR accumulator to scratch (R2: MfmaUtil 2.7%). LDS already limits
// to 1 block/CU, so min-waves=1 loses nothing.
template <int MODE>
__global__ __launch_bounds__(512, 1) void k_gemm256(
    const unsigned short* __restrict__ A,
    const unsigned short* __restrict__ Bmat,
    unsigned short* __restrict__ Qb,
    unsigned short* __restrict__ Kb,
    unsigned short* __restrict__ Vtb,
    const float* __restrict__ bo,
    float* __restrict__ outf) {
  __shared__ unsigned short smem[65536];   // 128 KiB: 2 bufs x (A0|A1|B0|B1) x 16 KiB
  const int NT = (MODE == 0) ? 768 : 256;
  const int XCHUNK = NT / 8;
  int bid = blockIdx.x;
  int swz = (bid % 8) * XCHUNK + bid / 8;   // bijective (NT % 8 == 0)
  int mt = swz & 127, nt = swz >> 7;
  int m0 = mt * 256, n0 = nt * 256;
  int tid = threadIdx.x;
  int wid = tid >> 6, lane = tid & 63;
  int lr = lane & 15, lg = lane >> 4;
  int wm = wid >> 2, wn = wid & 3;

  // ---- staging: linear LDS dest, inverse-swizzled global source (rule 21) ----
  int srow = wid * 16 + (lane >> 3);          // row within 128-row half (j=0)
  int scs = (lane & 7) ^ (lane >> 3);         // swizzled 16B-chunk index
  auto stage_tile = [&](int kb, int buf) {
#pragma unroll
    for (int H = 0; H < 4; ++H) {
      const unsigned short* gb = (H < 2) ? (A + (size_t)(m0 + H * 128) * 512)
                                         : (Bmat + (size_t)(n0 + (H - 2) * 128) * 512);
#pragma unroll
      for (int j = 0; j < 2; ++j) {
        int row = srow + j * 8;
        async16(gb + (size_t)row * 512 + kb * 64 + scs * 8,
                smem + buf * 32768 + H * 8192 + (wid * 2 + j) * 512);
      }
    }
  };
  // ---- swizzled ds_read of a 16x32 fragment ----
  int xcol0 = ((0 * 64 + lg * 16) ^ ((lr & 7) * 16)) >> 1;   // k32=0, in shorts
  int xcol1 = ((1 * 64 + lg * 16) ^ ((lr & 7) * 16)) >> 1;   // k32=1
  auto lda = [&](int buf, int mi, int k32) -> bf16x8 {
    int off = buf * 32768 + wm * 8192 + (mi * 16 + lr) * 64 + (k32 ? xcol1 : xcol0);
    return *(const bf16x8*)&smem[off];
  };
  auto ldb = [&](int buf, int ni, int k32) -> bf16x8 {
    int n = wn * 64 + ni * 16 + lr;
    int off = buf * 32768 + 16384 + (n >> 7) * 8192 + (n & 127) * 64 + (k32 ? xcol1 : xcol0);
    return *(const bf16x8*)&smem[off];
  };

  f32x4 acc[8][4];
#pragma unroll
  for (int mi = 0; mi < 8; ++mi)
#pragma unroll
    for (int ni = 0; ni < 4; ++ni) acc[mi][ni] = (f32x4){0.f, 0.f, 0.f, 0.f};

  // prologue: tiles 0,1 in flight; wait tile0 (8 loads/thread each)
  stage_tile(0, 0);
  stage_tile(1, 1);
  asm volatile("s_waitcnt vmcnt(8)" ::: "memory");
  __builtin_amdgcn_s_barrier();
  asm volatile("" ::: "memory");

  bf16x8 a03[4][2], a47[4][2], b01[2][2], b23[2][2];
#pragma unroll
  for (int t = 0; t < 8; ++t) {
    int buf = t & 1;
    // ---- phase 0: read A m0-3 + B n0-1; MFMA m0-3 x n0-1 ----
#pragma unroll
    for (int mi = 0; mi < 4; ++mi) { a03[mi][0] = lda(buf, mi, 0); a03[mi][1] = lda(buf, mi, 1); }
#pragma unroll
    for (int ni = 0; ni < 2; ++ni) { b01[ni][0] = ldb(buf, ni, 0); b01[ni][1] = ldb(buf, ni, 1); }
    __builtin_amdgcn_s_setprio(1);
#pragma unroll
    for (int mi = 0; mi < 4; ++mi)
#pragma unroll
      for (int ni = 0; ni < 2; ++ni)
#pragma unroll
        for (int k = 0; k < 2; ++k)
          acc[mi][ni] = __builtin_amdgcn_mfma_f32_16x16x32_bf16(a03[mi][k], b01[ni][k], acc[mi][ni], 0, 0, 0);
    __builtin_amdgcn_s_setprio(0);
    asm volatile("" ::: "memory");
    __builtin_amdgcn_s_barrier();
    asm volatile("" ::: "memory");
    // ---- phase 1: read A m4-7; MFMA m4-7 x n0-1 ----
#pragma unroll
    for (int mi = 0; mi < 4; ++mi) { a47[mi][0] = lda(buf, mi + 4, 0); a47[mi][1] = lda(buf, mi + 4, 1); }
    __builtin_amdgcn_s_setprio(1);
#pragma unroll
    for (int mi = 0; mi < 4; ++mi)
#pragma unroll
      for (int ni = 0; ni < 2; ++ni)
#pragma unroll
        for (int k = 0; k < 2; ++k)
          acc[mi + 4][ni] = __builtin_amdgcn_mfma_f32_16x16x32_bf16(a47[mi][k], b01[ni][k], acc[mi + 4][ni], 0, 0, 0);
    __builtin_amdgcn_s_setprio(0);
    asm volatile("" ::: "memory");
    __builtin_amdgcn_s_barrier();
    asm volatile("" ::: "memory");
    // ---- phase 2: read B n2-3; MFMA m4-7 x n2-3 ----
#pragma unroll
    for (int ni = 0; ni < 2; ++ni) { b23[ni][0] = ldb(buf, ni + 2, 0); b23[ni][1] = ldb(buf, ni + 2, 1); }
    __builtin_amdgcn_s_setprio(1);
#pragma unroll
    for (int mi = 0; mi < 4; ++mi)
#pragma unroll
      for (int ni = 0; ni < 2; ++ni)
#pragma unroll
        for (int k = 0; k < 2; ++k)
          acc[mi + 4][ni + 2] = __builtin_amdgcn_mfma_f32_16x16x32_bf16(a47[mi][k], b23[ni][k], acc[mi + 4][ni + 2], 0, 0, 0);
    __builtin_amdgcn_s_setprio(0);
    asm volatile("" ::: "memory");
    __builtin_amdgcn_s_barrier();
    asm volatile("" ::: "memory");
    // ---- phase 3: stage tile t+2 into buf (its reads all completed by ph2); MFMA m0-3 x n2-3 ----
    if (t < 6) stage_tile(t + 2, buf);
    __builtin_amdgcn_s_setprio(1);
#pragma unroll
    for (int mi = 0; mi < 4; ++mi)
#pragma unroll
      for (int ni = 0; ni < 2; ++ni)
#pragma unroll
        for (int k = 0; k < 2; ++k)
          acc[mi][ni + 2] = __builtin_amdgcn_mfma_f32_16x16x32_bf16(a03[mi][k], b23[ni][k], acc[mi][ni + 2], 0, 0, 0);
    __builtin_amdgcn_s_setprio(0);
    // counted wait: tile t+1 (issued last iter) landed; tile t+2's 8 loads stay in flight
    if (t < 6)      asm volatile("s_waitcnt vmcnt(8)" ::: "memory");
    else if (t == 6) asm volatile("s_waitcnt vmcnt(0)" ::: "memory");
    asm volatile("" ::: "memory");
    __builtin_amdgcn_s_barrier();
    asm volatile("" ::: "memory");
  }

  // ---- epilogue (LDS reuse needs full drain + barrier) ----
  asm volatile("s_waitcnt vmcnt(0) lgkmcnt(0)" ::: "memory");
  __builtin_amdgcn_s_barrier();
  asm volatile("" ::: "memory");

  if (MODE == 1) {
#pragma unroll
    for (int ni = 0; ni < 4; ++ni) {
      int n = n0 + wn * 64 + ni * 16 + lr;
      float bias = bo[n];
#pragma unroll
      for (int mi = 0; mi < 8; ++mi) {
        int m = m0 + wm * 128 + mi * 16 + lg * 4;
#pragma unroll
        for (int r = 0; r < 4; ++r)
          outf[(size_t)(m + r) * 512 + n] = acc[mi][ni][r] + bias;
      }
    }
  } else {
    int z = n0 >> 9;                       // 0=Q 1=K 2=V
    int bb = mt;                           // BM=256 == T: one batch per m-tile
    int h = ((n0 >> 6) & 7) + wn;          // wave owns exactly one head (64 cols)
    if (z < 2) {
      unsigned short* outp = (z ? Kb : Qb) + (size_t)(bb * 8 + h) * 16384;
#pragma unroll
      for (int ni = 0; ni < 4; ++ni) {
        int hd = ni * 16 + lr;
#pragma unroll
        for (int mi = 0; mi < 8; ++mi) {
          int tq = wm * 128 + mi * 16 + lg * 4;
#pragma unroll
          for (int r = 0; r < 4; ++r)
            outp[(size_t)(tq + r) * 64 + hd] = f2bf(acc[mi][ni][r]);
        }
      }
    } else {
      // V: per-wave LDS transpose (private 16 KiB region), 16B stores to [B,H,HD,T]
      unsigned short* Vls = smem + wid * 8192;
      unsigned short* outp = Vtb + (size_t)(bb * 8 + h) * 16384;
#pragma unroll
      for (int ni = 0; ni < 4; ++ni) {
#pragma unroll
        for (int mi = 0; mi < 8; ++mi) {
          u16x4 v;
          v[0] = f2bf(acc[mi][ni][0]); v[1] = f2bf(acc[mi][ni][1]);
          v[2] = f2bf(acc[mi][ni][2]); v[3] = f2bf(acc[mi][ni][3]);
          *(u16x4*)&Vls[lr * 136 + mi * 16 + lg * 4] = v;
        }
        int hd = ni * 16 + (lane >> 2);
        int tq0 = wm * 128 + (lane & 3) * 32;
#pragma unroll
        for (int jj = 0; jj < 4; ++jj) {
          u16x8 v = *(const u16x8*)&Vls[(lane >> 2) * 136 + (lane & 3) * 32 + jj * 8];
          *(u16x8*)&outp[(size_t)hd * 256 + tq0 + jj * 8] = v;
        }
      }
    }
  }
}

// ---------------- fused causal attention: barrier-free, no K/V staging ----------------
// K/V per (b,h) is 64 KiB -> L1/L2-resident; staging it was pure overhead (1 block/CU).
// grid (1024, 4): bh = blockIdx.x, q = blockIdx.y; wave owns chunk ci = wid*4 + q.
// LDS: only per-wave P buffer (35 KiB) -> 4 blocks/CU -> 16 waves/CU, zero barriers.
__global__ __launch_bounds__(256) void k_attn(
    const unsigned short* __restrict__ Qb,
    const unsigned short* __restrict__ Kb,
    const unsigned short* __restrict__ Vtb,
    unsigned short* __restrict__ Ob) {  // [B,T,512] bf16 (concat heads)
  __shared__ unsigned short Ps[4][16][280];
  int bh = blockIdx.x, q = blockIdx.y;
  int tid = threadIdx.x, wid = tid >> 6, lane = tid & 63, lr = lane & 15, lg = lane >> 4;
  int bb = bh >> 3, h = bh & 7;
  int ci = wid * 4 + q;      // 0..15; block sums balanced (28..40 tiles)
  int t0 = ci * 16;
  int ntV = ci + 1;          // K-tiles with any valid (s <= t) data
  int ntE = (ntV + 1) & ~1;  // rounded even for K=32 PV steps
  int nk32 = ntE >> 1;
  const unsigned short* Kbase = Kb + (size_t)bh * 16384;
  const unsigned short* Vbase = Vtb + (size_t)bh * 16384;
  const unsigned short* qsrc = Qb + (size_t)bh * 16384 + (t0 + lr) * 64 + lg * 8;
  bf16x8 aq0 = *(const bf16x8*)qsrc;
  bf16x8 aq1 = *(const bf16x8*)(qsrc + 32);
  f32x4 acc[16];
#pragma unroll
  for (int nt = 0; nt < 16; ++nt)
    if (nt < ntE) acc[nt] = (f32x4){0.f, 0.f, 0.f, 0.f};
#pragma unroll
  for (int nt = 0; nt < 16; ++nt)
    if (nt < ntV) {
      bf16x8 b0 = *(const bf16x8*)&Kbase[(nt * 16 + lr) * 64 + lg * 8];
      acc[nt] = __builtin_amdgcn_mfma_f32_16x16x32_bf16(aq0, b0, acc[nt], 0, 0, 0);
      bf16x8 b1 = *(const bf16x8*)&Kbase[(nt * 16 + lr) * 64 + 32 + lg * 8];
      acc[nt] = __builtin_amdgcn_mfma_f32_16x16x32_bf16(aq1, b1, acc[nt], 0, 0, 0);
    }
  // scale + causal mask + row max
  float mrow[4] = {-3.0e38f, -3.0e38f, -3.0e38f, -3.0e38f};
#pragma unroll
  for (int nt = 0; nt < 16; ++nt)
    if (nt < ntE) {
#pragma unroll
      for (int r = 0; r < 4; ++r) {
        float v = acc[nt][r] * 0.125f;
        if (nt * 16 + lr > t0 + lg * 4 + r) v = -1.0e30f;
        acc[nt][r] = v;
        mrow[r] = fmaxf(mrow[r], v);
      }
    }
#pragma unroll
  for (int r = 0; r < 4; ++r) {
    mrow[r] = fmaxf(mrow[r], __shfl_xor(mrow[r], 1));
    mrow[r] = fmaxf(mrow[r], __shfl_xor(mrow[r], 2));
    mrow[r] = fmaxf(mrow[r], __shfl_xor(mrow[r], 4));
    mrow[r] = fmaxf(mrow[r], __shfl_xor(mrow[r], 8));
  }
  float srow[4] = {0.f, 0.f, 0.f, 0.f};
#pragma unroll
  for (int nt = 0; nt < 16; ++nt)
    if (nt < ntE) {
#pragma unroll
      for (int r = 0; r < 4; ++r) {
        float p = __expf(acc[nt][r] - mrow[r]);
        srow[r] += p;
        Ps[wid][lg * 4 + r][nt * 16 + lr] = f2bf(p);
      }
    }
#pragma unroll
  for (int r = 0; r < 4; ++r) {
    srow[r] += __shfl_xor(srow[r], 1);
    srow[r] += __shfl_xor(srow[r], 2);
    srow[r] += __shfl_xor(srow[r], 4);
    srow[r] += __shfl_xor(srow[r], 8);
  }
  __threadfence_block();  // order P LDS writes before same-wave reads
  f32x4 aco[4];
#pragma unroll
  for (int vt = 0; vt < 4; ++vt) aco[vt] = (f32x4){0.f, 0.f, 0.f, 0.f};
#pragma unroll
  for (int k32 = 0; k32 < 8; ++k32)
    if (k32 < nk32) {
      bf16x8 pa = *(const bf16x8*)&Ps[wid][lr][k32 * 32 + lg * 8];
#pragma unroll
      for (int vt = 0; vt < 4; ++vt) {
        bf16x8 vb = *(const bf16x8*)&Vbase[(vt * 16 + lr) * 256 + k32 * 32 + lg * 8];
        aco[vt] = __builtin_amdgcn_mfma_f32_16x16x32_bf16(pa, vb, aco[vt], 0, 0, 0);
      }
    }
#pragma unroll
  for (int r = 0; r < 4; ++r) {
    float inv = 1.0f / srow[r];
    unsigned short* o = Ob + ((size_t)(bb * 256 + t0 + lg * 4 + r)) * 512 + h * 64;
#pragma unroll
    for (int vt = 0; vt < 4; ++vt) o[vt * 16 + lr] = f2bf(aco[vt][r] * inv);
  }
}

extern "C" void kernel_launch(void* const* d_in, const int* in_sizes, int n_in,
                              void* d_out, int out_size, void* d_ws, size_t ws_size,
                              hipStream_t stream) {
  (void)in_sizes; (void)n_in; (void)out_size; (void)ws_size;
  const float* x = (const float*)d_in[0];
  const float* Wq = (const float*)d_in[1];
  const float* Wk = (const float*)d_in[2];
  const float* Wv = (const float*)d_in[3];
  const float* Wo = (const float*)d_in[4];
  const float* bo = (const float*)d_in[5];
  float* out = (float*)d_out;
  char* ws = (char*)d_ws;
  const size_t MB = 1024 * 1024;
  unsigned short* Qb = (unsigned short*)(ws);             // 32 MB
  unsigned short* Kb = (unsigned short*)(ws + 32 * MB);   // 32 MB
  unsigned short* Vtb = (unsigned short*)(ws + 64 * MB);  // 32 MB
  unsigned short* xb = (unsigned short*)(ws + 96 * MB);   // 32 MB (reused as attn out)
  unsigned short* Wqt = (unsigned short*)(ws + 128 * MB); // [1536][512] contiguous (q,k,v)
  unsigned short* Wkt = Wqt + 262144;
  unsigned short* Wvt = Wkt + 262144;
  unsigned short* Wot = Wvt + 262144;

  hipLaunchKernelGGL(k_convert_x, dim3(8192), dim3(256), 0, stream, x, xb);
  hipLaunchKernelGGL(k_transpose_w, dim3(1, 8, 8), dim3(256), 0, stream, Wq, Wqt, 512, 64);
  hipLaunchKernelGGL(k_transpose_w, dim3(1, 8, 8), dim3(256), 0, stream, Wk, Wkt, 512, 64);
  hipLaunchKernelGGL(k_transpose_w, dim3(1, 8, 8), dim3(256), 0, stream, Wv, Wvt, 512, 64);
  hipLaunchKernelGGL(k_transpose_w, dim3(8, 8, 1), dim3(256), 0, stream, Wo, Wot, 512, 512);
  hipLaunchKernelGGL((k_gemm256<0>), dim3(768), dim3(512), 0, stream,
                     xb, Wqt, Qb, Kb, Vtb, bo, out);
  hipLaunchKernelGGL(k_attn, dim3(1024, 4), dim3(256), 0, stream, Qb, Kb, Vtb, xb);
  hipLaunchKernelGGL((k_gemm256<1>), dim3(256), dim3(512), 0, stream,
                     xb, Wot, Qb, Kb, Vtb, bo, out);
}

// Round 6
// 221.149 us; speedup vs baseline: 1.0171x; 1.0171x over previous
//
#include <hip/hip_runtime.h>
#include <hip/hip_bf16.h>

typedef __bf16 bf16x8 __attribute__((ext_vector_type(8)));
typedef __bf16 bf16x4 __attribute__((ext_vector_type(4)));
typedef float f32x4 __attribute__((ext_vector_type(4)));
typedef unsigned short u16x8 __attribute__((ext_vector_type(8)));
typedef unsigned short u16x4 __attribute__((ext_vector_type(4)));

// B=128, T=256, D=512, H=8, HD=64. M = B*T = 32768.

__device__ __forceinline__ unsigned short f2bf(float f) {
  unsigned u = __float_as_uint(f);
  u += 0x7fffu + ((u >> 16) & 1u);   // RNE
  return (unsigned short)(u >> 16);
}

// async global->LDS, 16B per lane. LDS dest wave-uniform; HW adds lane*16.
__device__ __forceinline__ void async16(const void* g, void* l) {
  __builtin_amdgcn_global_load_lds(
      (const __attribute__((address_space(1))) void*)g,
      (__attribute__((address_space(3))) void*)l, 16, 0, 0);
}

// ---------------- x fp32 -> bf16 ----------------
__global__ __launch_bounds__(256) void k_convert_x(const float* __restrict__ in,
                                                   unsigned short* __restrict__ out) {
  int i = blockIdx.x * 256 + threadIdx.x;
  const float4* p = (const float4*)in + (size_t)i * 2;
  float4 a = p[0], b = p[1];
  u16x8 o;
  o[0] = f2bf(a.x); o[1] = f2bf(a.y); o[2] = f2bf(a.z); o[3] = f2bf(a.w);
  o[4] = f2bf(b.x); o[5] = f2bf(b.y); o[6] = f2bf(b.z); o[7] = f2bf(b.w);
  *((u16x8*)out + i) = o;
}

// ---------------- W fp32 [batch][rows][cols] -> bf16 [batch][cols][rows] ----------------
__global__ __launch_bounds__(256) void k_transpose_w(const float* __restrict__ in,
                                                     unsigned short* __restrict__ out,
                                                     int rows, int cols) {
  __shared__ unsigned short tile[64][72];
  int c0 = blockIdx.x * 64, r0 = blockIdx.y * 64;
  const float* inb = in + (size_t)blockIdx.z * rows * cols;
  unsigned short* outb = out + (size_t)blockIdx.z * rows * cols;
  int tid = threadIdx.x;
  int r = tid >> 2, cq = (tid & 3) * 16;
  const float* src = inb + (size_t)(r0 + r) * cols + c0 + cq;
#pragma unroll
  for (int i = 0; i < 16; i += 4) {
    float4 v = *(const float4*)(src + i);
    tile[r][cq + i + 0] = f2bf(v.x);
    tile[r][cq + i + 1] = f2bf(v.y);
    tile[r][cq + i + 2] = f2bf(v.z);
    tile[r][cq + i + 3] = f2bf(v.w);
  }
  __syncthreads();
  int cr = tid >> 2, rq = (tid & 3) * 16;
  u16x8 o0, o1;
#pragma unroll
  for (int i = 0; i < 8; ++i) o0[i] = tile[rq + i][cr];
#pragma unroll
  for (int i = 0; i < 8; ++i) o1[i] = tile[rq + 8 + i][cr];
  unsigned short* dst = outb + (size_t)(c0 + cr) * rows + r0 + rq;
  *(u16x8*)dst = o0;
  *(u16x8*)(dst + 8) = o1;
}

// ---------------- 256x256x(K=512) 8-phase GEMM, C = A * Bmat^T ----------------
template <int MODE>
__global__ __launch_bounds__(512, 1) void k_gemm256(
    const unsigned short* __restrict__ A,
    const unsigned short* __restrict__ Bmat,
    unsigned short* __restrict__ Qb,
    unsigned short* __restrict__ Kb,
    unsigned short* __restrict__ Vtb,
    const float* __restrict__ bo,
    float* __restrict__ outf) {
  __shared__ unsigned short smem[65536];   // 128 KiB: 2 bufs x (A0|A1|B0|B1) x 16 KiB
  const int NT = (MODE == 0) ? 768 : 256;
  const int XCHUNK = NT / 8;
  int bid = blockIdx.x;
  int swz = (bid % 8) * XCHUNK + bid / 8;   // bijective (NT % 8 == 0)
  int mt = swz & 127, nt = swz >> 7;
  int m0 = mt * 256, n0 = nt * 256;
  int tid = threadIdx.x;
  int wid = tid >> 6, lane = tid & 63;
  int lr = lane & 15, lg = lane >> 4;
  int wm = wid >> 2, wn = wid & 3;

  int srow = wid * 16 + (lane >> 3);          // row within 128-row half (j=0)
  int scs = (lane & 7) ^ (lane >> 3);         // swizzled 16B-chunk index
  auto stage_tile = [&](int kb, int buf) {
#pragma unroll
    for (int H = 0; H < 4; ++H) {
      const unsigned short* gb = (H < 2) ? (A + (size_t)(m0 + H * 128) * 512)
                                         : (Bmat + (size_t)(n0 + (H - 2) * 128) * 512);
#pragma unroll
      for (int j = 0; j < 2; ++j) {
        int row = srow + j * 8;
        async16(gb + (size_t)row * 512 + kb * 64 + scs * 8,
                smem + buf * 32768 + H * 8192 + (wid * 2 + j) * 512);
      }
    }
  };
  int xcol0 = ((0 * 64 + lg * 16) ^ ((lr & 7) * 16)) >> 1;   // k32=0, in shorts
  int xcol1 = ((1 * 64 + lg * 16) ^ ((lr & 7) * 16)) >> 1;   // k32=1
  auto lda = [&](int buf, int mi, int k32) -> bf16x8 {
    int off = buf * 32768 + wm * 8192 + (mi * 16 + lr) * 64 + (k32 ? xcol1 : xcol0);
    return *(const bf16x8*)&smem[off];
  };
  auto ldb = [&](int buf, int ni, int k32) -> bf16x8 {
    int n = wn * 64 + ni * 16 + lr;
    int off = buf * 32768 + 16384 + (n >> 7) * 8192 + (n & 127) * 64 + (k32 ? xcol1 : xcol0);
    return *(const bf16x8*)&smem[off];
  };

  f32x4 acc[8][4];
#pragma unroll
  for (int mi = 0; mi < 8; ++mi)
#pragma unroll
    for (int ni = 0; ni < 4; ++ni) acc[mi][ni] = (f32x4){0.f, 0.f, 0.f, 0.f};

  stage_tile(0, 0);
  stage_tile(1, 1);
  asm volatile("s_waitcnt vmcnt(8)" ::: "memory");
  __builtin_amdgcn_s_barrier();
  asm volatile("" ::: "memory");

  bf16x8 a03[4][2], a47[4][2], b01[2][2], b23[2][2];
#pragma unroll
  for (int t = 0; t < 8; ++t) {
    int buf = t & 1;
    // ---- phase 0 ----
#pragma unroll
    for (int mi = 0; mi < 4; ++mi) { a03[mi][0] = lda(buf, mi, 0); a03[mi][1] = lda(buf, mi, 1); }
#pragma unroll
    for (int ni = 0; ni < 2; ++ni) { b01[ni][0] = ldb(buf, ni, 0); b01[ni][1] = ldb(buf, ni, 1); }
    __builtin_amdgcn_s_setprio(1);
#pragma unroll
    for (int mi = 0; mi < 4; ++mi)
#pragma unroll
      for (int ni = 0; ni < 2; ++ni)
#pragma unroll
        for (int k = 0; k < 2; ++k)
          acc[mi][ni] = __builtin_amdgcn_mfma_f32_16x16x32_bf16(a03[mi][k], b01[ni][k], acc[mi][ni], 0, 0, 0);
    __builtin_amdgcn_s_setprio(0);
    asm volatile("" ::: "memory");
    __builtin_amdgcn_s_barrier();
    asm volatile("" ::: "memory");
    // ---- phase 1 ----
#pragma unroll
    for (int mi = 0; mi < 4; ++mi) { a47[mi][0] = lda(buf, mi + 4, 0); a47[mi][1] = lda(buf, mi + 4, 1); }
    __builtin_amdgcn_s_setprio(1);
#pragma unroll
    for (int mi = 0; mi < 4; ++mi)
#pragma unroll
      for (int ni = 0; ni < 2; ++ni)
#pragma unroll
        for (int k = 0; k < 2; ++k)
          acc[mi + 4][ni] = __builtin_amdgcn_mfma_f32_16x16x32_bf16(a47[mi][k], b01[ni][k], acc[mi + 4][ni], 0, 0, 0);
    __builtin_amdgcn_s_setprio(0);
    asm volatile("" ::: "memory");
    __builtin_amdgcn_s_barrier();
    asm volatile("" ::: "memory");
    // ---- phase 2 ----
#pragma unroll
    for (int ni = 0; ni < 2; ++ni) { b23[ni][0] = ldb(buf, ni + 2, 0); b23[ni][1] = ldb(buf, ni + 2, 1); }
    __builtin_amdgcn_s_setprio(1);
#pragma unroll
    for (int mi = 0; mi < 4; ++mi)
#pragma unroll
      for (int ni = 0; ni < 2; ++ni)
#pragma unroll
        for (int k = 0; k < 2; ++k)
          acc[mi + 4][ni + 2] = __builtin_amdgcn_mfma_f32_16x16x32_bf16(a47[mi][k], b23[ni][k], acc[mi + 4][ni + 2], 0, 0, 0);
    __builtin_amdgcn_s_setprio(0);
    asm volatile("" ::: "memory");
    __builtin_amdgcn_s_barrier();
    asm volatile("" ::: "memory");
    // ---- phase 3 ----
    if (t < 6) stage_tile(t + 2, buf);
    __builtin_amdgcn_s_setprio(1);
#pragma unroll
    for (int mi = 0; mi < 4; ++mi)
#pragma unroll
      for (int ni = 0; ni < 2; ++ni)
#pragma unroll
        for (int k = 0; k < 2; ++k)
          acc[mi][ni + 2] = __builtin_amdgcn_mfma_f32_16x16x32_bf16(a03[mi][k], b23[ni][k], acc[mi][ni + 2], 0, 0, 0);
    __builtin_amdgcn_s_setprio(0);
    if (t < 6)      asm volatile("s_waitcnt vmcnt(8)" ::: "memory");
    else if (t == 6) asm volatile("s_waitcnt vmcnt(0)" ::: "memory");
    asm volatile("" ::: "memory");
    __builtin_amdgcn_s_barrier();
    asm volatile("" ::: "memory");
  }

  asm volatile("s_waitcnt vmcnt(0) lgkmcnt(0)" ::: "memory");
  __builtin_amdgcn_s_barrier();
  asm volatile("" ::: "memory");

  if (MODE == 1) {
#pragma unroll
    for (int ni = 0; ni < 4; ++ni) {
      int n = n0 + wn * 64 + ni * 16 + lr;
      float bias = bo[n];
#pragma unroll
      for (int mi = 0; mi < 8; ++mi) {
        int m = m0 + wm * 128 + mi * 16 + lg * 4;
#pragma unroll
        for (int r = 0; r < 4; ++r)
          outf[(size_t)(m + r) * 512 + n] = acc[mi][ni][r] + bias;
      }
    }
  } else {
    int z = n0 >> 9;                       // 0=Q 1=K 2=V
    int bb = mt;
    int h = ((n0 >> 6) & 7) + wn;
    if (z < 2) {
      unsigned short* outp = (z ? Kb : Qb) + (size_t)(bb * 8 + h) * 16384;
#pragma unroll
      for (int ni = 0; ni < 4; ++ni) {
        int hd = ni * 16 + lr;
#pragma unroll
        for (int mi = 0; mi < 8; ++mi) {
          int tq = wm * 128 + mi * 16 + lg * 4;
#pragma unroll
          for (int r = 0; r < 4; ++r)
            outp[(size_t)(tq + r) * 64 + hd] = f2bf(acc[mi][ni][r]);
        }
      }
    } else {
      unsigned short* Vls = smem + wid * 8192;
      unsigned short* outp = Vtb + (size_t)(bb * 8 + h) * 16384;
#pragma unroll
      for (int ni = 0; ni < 4; ++ni) {
#pragma unroll
        for (int mi = 0; mi < 8; ++mi) {
          u16x4 v;
          v[0] = f2bf(acc[mi][ni][0]); v[1] = f2bf(acc[mi][ni][1]);
          v[2] = f2bf(acc[mi][ni][2]); v[3] = f2bf(acc[mi][ni][3]);
          *(u16x4*)&Vls[lr * 136 + mi * 16 + lg * 4] = v;
        }
        int hd = ni * 16 + (lane >> 2);
        int tq0 = wm * 128 + (lane & 3) * 32;
#pragma unroll
        for (int jj = 0; jj < 4; ++jj) {
          u16x8 v = *(const u16x8*)&Vls[(lane >> 2) * 136 + (lane & 3) * 32 + jj * 8];
          *(u16x8*)&outp[(size_t)hd * 256 + tq0 + jj * 8] = v;
        }
      }
    }
  }
}

// ---------------- fused causal attention: swapped operands, packed P ----------------
// S^T = mfma(K,Q): lane owns row t=lr, 4 consecutive s per reg -> packed 8B P-store,
// lane-local row max/sum (+2 shfl), PV = mfma(Vt,P) -> packed 8B out store, inv in-lane.
// XCD-grouped swizzle: each XCD gets 512 consecutive wg -> K/V working set 2MB < L2.
__global__ __launch_bounds__(256) void k_attn(
    const unsigned short* __restrict__ Qb,
    const unsigned short* __restrict__ Kb,
    const unsigned short* __restrict__ Vtb,
    unsigned short* __restrict__ Ob) {  // [B,T,512] bf16 (concat heads)
  __shared__ unsigned short Ps[4][16][280];
  int bid = blockIdx.x;
  int wg = (bid & 7) * 512 + (bid >> 3);   // XCD-contiguous (4096 % 8 == 0)
  int bh = wg >> 2, q = wg & 3;
  int tid = threadIdx.x, wid = tid >> 6, lane = tid & 63, lr = lane & 15, lg = lane >> 4;
  int bb = bh >> 3, h = bh & 7;
  int ci = wid * 4 + q;      // 0..15
  int t0 = ci * 16;
  int ntV = ci + 1;          // K-tiles with any valid (s <= t) data
  int ntE = (ntV + 1) & ~1;  // rounded even for K=32 PV steps
  int nk32 = ntE >> 1;
  const unsigned short* Kbase = Kb + (size_t)bh * 16384;
  const unsigned short* Vbase = Vtb + (size_t)bh * 16384;
  const unsigned short* qsrc = Qb + (size_t)bh * 16384 + (t0 + lr) * 64 + lg * 8;
  bf16x8 bq0 = *(const bf16x8*)qsrc;          // B-operand: b[col=t=lr][k=lg*8+j]
  bf16x8 bq1 = *(const bf16x8*)(qsrc + 32);
  f32x4 acc[16];
#pragma unroll
  for (int nt = 0; nt < 16; ++nt)
    if (nt < ntE) acc[nt] = (f32x4){0.f, 0.f, 0.f, 0.f};
#pragma unroll
  for (int nt = 0; nt < 16; ++nt)
    if (nt < ntV) {
      bf16x8 ak0 = *(const bf16x8*)&Kbase[(nt * 16 + lr) * 64 + lg * 8];   // a[row=s][k]
      acc[nt] = __builtin_amdgcn_mfma_f32_16x16x32_bf16(ak0, bq0, acc[nt], 0, 0, 0);
      bf16x8 ak1 = *(const bf16x8*)&Kbase[(nt * 16 + lr) * 64 + 32 + lg * 8];
      acc[nt] = __builtin_amdgcn_mfma_f32_16x16x32_bf16(ak1, bq1, acc[nt], 0, 0, 0);
    }
  // acc[nt][r] = S[t=t0+lr][s=nt*16+lg*4+r]  (S^T layout: col=t, row=s)
  int trow = t0 + lr;
  float m = -3.0e38f;
#pragma unroll
  for (int nt = 0; nt < 16; ++nt)
    if (nt < ntE) {
#pragma unroll
      for (int r = 0; r < 4; ++r) {
        float v = acc[nt][r] * 0.125f;
        if (nt * 16 + lg * 4 + r > trow) v = -1.0e30f;
        acc[nt][r] = v;
        m = fmaxf(m, v);
      }
    }
  m = fmaxf(m, __shfl_xor(m, 16));
  m = fmaxf(m, __shfl_xor(m, 32));
  float s = 0.f;
#pragma unroll
  for (int nt = 0; nt < 16; ++nt)
    if (nt < ntE) {
      bf16x4 pk;
#pragma unroll
      for (int r = 0; r < 4; ++r) {
        float p = __expf(acc[nt][r] - m);
        s += p;
        pk[r] = (__bf16)p;
      }
      *(bf16x4*)&Ps[wid][lr][nt * 16 + lg * 4] = pk;   // packed 8B
    }
  s += __shfl_xor(s, 16);
  s += __shfl_xor(s, 32);
  float inv = 1.0f / s;
  __threadfence_block();  // order P LDS writes before same-wave reads
  f32x4 aco[4];
#pragma unroll
  for (int vt = 0; vt < 4; ++vt) aco[vt] = (f32x4){0.f, 0.f, 0.f, 0.f};
#pragma unroll
  for (int k32 = 0; k32 < 8; ++k32)
    if (k32 < nk32) {
      bf16x8 pb = *(const bf16x8*)&Ps[wid][lr][k32 * 32 + lg * 8];   // b[col=t][k=s]
#pragma unroll
      for (int vt = 0; vt < 4; ++vt) {
        bf16x8 av = *(const bf16x8*)&Vbase[(vt * 16 + lr) * 256 + k32 * 32 + lg * 8]; // a[row=hd][k=s]
        aco[vt] = __builtin_amdgcn_mfma_f32_16x16x32_bf16(av, pb, aco[vt], 0, 0, 0);
      }
    }
  // aco[vt][r] = O[t=t0+lr][hd=vt*16+lg*4+r]
  unsigned short* obase = Ob + (size_t)(bb * 256 + trow) * 512 + h * 64 + lg * 4;
#pragma unroll
  for (int vt = 0; vt < 4; ++vt) {
    bf16x4 ov;
#pragma unroll
    for (int r = 0; r < 4; ++r) ov[r] = (__bf16)(aco[vt][r] * inv);
    *(bf16x4*)(obase + vt * 16) = ov;   // packed 8B
  }
}

extern "C" void kernel_launch(void* const* d_in, const int* in_sizes, int n_in,
                              void* d_out, int out_size, void* d_ws, size_t ws_size,
                              hipStream_t stream) {
  (void)in_sizes; (void)n_in; (void)out_size; (void)ws_size;
  const float* x = (const float*)d_in[0];
  const float* Wq = (const float*)d_in[1];
  const float* Wk = (const float*)d_in[2];
  const float* Wv = (const float*)d_in[3];
  const float* Wo = (const float*)d_in[4];
  const float* bo = (const float*)d_in[5];
  float* out = (float*)d_out;
  char* ws = (char*)d_ws;
  const size_t MB = 1024 * 1024;
  unsigned short* Qb = (unsigned short*)(ws);             // 32 MB
  unsigned short* Kb = (unsigned short*)(ws + 32 * MB);   // 32 MB
  unsigned short* Vtb = (unsigned short*)(ws + 64 * MB);  // 32 MB
  unsigned short* xb = (unsigned short*)(ws + 96 * MB);   // 32 MB (reused as attn out)
  unsigned short* Wqt = (unsigned short*)(ws + 128 * MB); // [1536][512] contiguous (q,k,v)
  unsigned short* Wkt = Wqt + 262144;
  unsigned short* Wvt = Wkt + 262144;
  unsigned short* Wot = Wvt + 262144;

  hipLaunchKernelGGL(k_convert_x, dim3(8192), dim3(256), 0, stream, x, xb);
  hipLaunchKernelGGL(k_transpose_w, dim3(1, 8, 8), dim3(256), 0, stream, Wq, Wqt, 512, 64);
  hipLaunchKernelGGL(k_transpose_w, dim3(1, 8, 8), dim3(256), 0, stream, Wk, Wkt, 512, 64);
  hipLaunchKernelGGL(k_transpose_w, dim3(1, 8, 8), dim3(256), 0, stream, Wv, Wvt, 512, 64);
  hipLaunchKernelGGL(k_transpose_w, dim3(8, 8, 1), dim3(256), 0, stream, Wo, Wot, 512, 512);
  hipLaunchKernelGGL((k_gemm256<0>), dim3(768), dim3(512), 0, stream,
                     xb, Wqt, Qb, Kb, Vtb, bo, out);
  hipLaunchKernelGGL(k_attn, dim3(4096), dim3(256), 0, stream, Qb, Kb, Vtb, xb);
  hipLaunchKernelGGL((k_gemm256<1>), dim3(256), dim3(512), 0, stream,
                     xb, Wot, Qb, Kb, Vtb, bo, out);
}

// Round 7
// 176.565 us; speedup vs baseline: 1.2740x; 1.2525x over previous
//
#include <hip/hip_runtime.h>
#include <hip/hip_bf16.h>

typedef __bf16 bf16x8 __attribute__((ext_vector_type(8)));
typedef __bf16 bf16x4 __attribute__((ext_vector_type(4)));
typedef float f32x4 __attribute__((ext_vector_type(4)));
typedef unsigned short u16x8 __attribute__((ext_vector_type(8)));

// B=128, T=256, D=512, H=8, HD=64. M = B*T = 32768.

__device__ __forceinline__ unsigned short f2bf(float f) {
  unsigned u = __float_as_uint(f);
  u += 0x7fffu + ((u >> 16) & 1u);   // RNE
  return (unsigned short)(u >> 16);
}

__device__ __forceinline__ bf16x4 cvt4(f32x4 v) {
  bf16x4 o;
  o[0] = (__bf16)v[0]; o[1] = (__bf16)v[1]; o[2] = (__bf16)v[2]; o[3] = (__bf16)v[3];
  return o;
}

// async global->LDS, 16B per lane. LDS dest wave-uniform; HW adds lane*16.
__device__ __forceinline__ void async16(const void* g, void* l) {
  __builtin_amdgcn_global_load_lds(
      (const __attribute__((address_space(1))) void*)g,
      (__attribute__((address_space(3))) void*)l, 16, 0, 0);
}

// ---------------- x fp32 -> bf16 ----------------
__global__ __launch_bounds__(256) void k_convert_x(const float* __restrict__ in,
                                                   unsigned short* __restrict__ out) {
  int i = blockIdx.x * 256 + threadIdx.x;
  const float4* p = (const float4*)in + (size_t)i * 2;
  float4 a = p[0], b = p[1];
  u16x8 o;
  o[0] = f2bf(a.x); o[1] = f2bf(a.y); o[2] = f2bf(a.z); o[3] = f2bf(a.w);
  o[4] = f2bf(b.x); o[5] = f2bf(b.y); o[6] = f2bf(b.z); o[7] = f2bf(b.w);
  *((u16x8*)out + i) = o;
}

// ---------------- W fp32 [batch][rows][cols] -> bf16 [batch][cols][rows] ----------------
__global__ __launch_bounds__(256) void k_transpose_w(const float* __restrict__ in,
                                                     unsigned short* __restrict__ out,
                                                     int rows, int cols) {
  __shared__ unsigned short tile[64][72];
  int c0 = blockIdx.x * 64, r0 = blockIdx.y * 64;
  const float* inb = in + (size_t)blockIdx.z * rows * cols;
  unsigned short* outb = out + (size_t)blockIdx.z * rows * cols;
  int tid = threadIdx.x;
  int r = tid >> 2, cq = (tid & 3) * 16;
  const float* src = inb + (size_t)(r0 + r) * cols + c0 + cq;
#pragma unroll
  for (int i = 0; i < 16; i += 4) {
    float4 v = *(const float4*)(src + i);
    tile[r][cq + i + 0] = f2bf(v.x);
    tile[r][cq + i + 1] = f2bf(v.y);
    tile[r][cq + i + 2] = f2bf(v.z);
    tile[r][cq + i + 3] = f2bf(v.w);
  }
  __syncthreads();
  int cr = tid >> 2, rq = (tid & 3) * 16;
  u16x8 o0, o1;
#pragma unroll
  for (int i = 0; i < 8; ++i) o0[i] = tile[rq + i][cr];
#pragma unroll
  for (int i = 0; i < 8; ++i) o1[i] = tile[rq + 8 + i][cr];
  unsigned short* dst = outb + (size_t)(c0 + cr) * rows + r0 + rq;
  *(u16x8*)dst = o0;
  *(u16x8*)(dst + 8) = o1;
}

// ---------------- 256x256x(K=512) 8-phase GEMM ----------------
// KIND 0: x * Wqk^T -> Q,K [B,H,T,HD] bf16 (swapped mfma: packed hd stores). grid 512.
// KIND 1: a * Wo^T + bo -> fp32 out (swapped mfma: packed float4 stores).   grid 256.
// KIND 2: x * Wv^T -> V^T [B,H,HD,T] bf16 (normal mfma: packed t stores).   grid 256.
// Block order: XCD-chunked, nt-inner (consecutive same-XCD blocks share the A panel).
template <int KIND>
__global__ __launch_bounds__(512, 1) void k_gemmP(
    const unsigned short* __restrict__ A,
    const unsigned short* __restrict__ Bmat,
    unsigned short* __restrict__ O0,
    unsigned short* __restrict__ O1,
    const float* __restrict__ bo,
    float* __restrict__ outf) {
  __shared__ unsigned short smem[65536];   // 128 KiB: 2 bufs x (A0|A1|B0|B1) x 16 KiB
  const int P = (KIND == 0) ? 64 : 32;     // blocks per XCD
  int xcd = blockIdx.x & 7, g = blockIdx.x >> 3;
  int w = xcd * P + g;
  int mt, nt;
  if (KIND == 0) { mt = w >> 2; nt = w & 3; }
  else           { mt = w >> 1; nt = w & 1; }
  int m0 = mt * 256, n0 = nt * 256;
  int tid = threadIdx.x;
  int wid = tid >> 6, lane = tid & 63;
  int lr = lane & 15, lg = lane >> 4;
  int wm = wid >> 2, wn = wid & 3;

  int srow = wid * 16 + (lane >> 3);
  int scs = (lane & 7) ^ (lane >> 3);         // swizzled 16B-chunk index
  auto stage_tile = [&](int kb, int buf) {
#pragma unroll
    for (int H = 0; H < 4; ++H) {
      const unsigned short* gb = (H < 2) ? (A + (size_t)(m0 + H * 128) * 512)
                                         : (Bmat + (size_t)(n0 + (H - 2) * 128) * 512);
#pragma unroll
      for (int j = 0; j < 2; ++j) {
        int row = srow + j * 8;
        async16(gb + (size_t)row * 512 + kb * 64 + scs * 8,
                smem + buf * 32768 + H * 8192 + (wid * 2 + j) * 512);
      }
    }
  };
  int xcol0 = ((0 * 64 + lg * 16) ^ ((lr & 7) * 16)) >> 1;
  int xcol1 = ((1 * 64 + lg * 16) ^ ((lr & 7) * 16)) >> 1;
  auto lda = [&](int buf, int mi, int k32) -> bf16x8 {
    int off = buf * 32768 + wm * 8192 + (mi * 16 + lr) * 64 + (k32 ? xcol1 : xcol0);
    return *(const bf16x8*)&smem[off];
  };
  auto ldb = [&](int buf, int ni, int k32) -> bf16x8 {
    int n = wn * 64 + ni * 16 + lr;
    int off = buf * 32768 + 16384 + (n >> 7) * 8192 + (n & 127) * 64 + (k32 ? xcol1 : xcol0);
    return *(const bf16x8*)&smem[off];
  };

  f32x4 acc[8][4];
#pragma unroll
  for (int mi = 0; mi < 8; ++mi)
#pragma unroll
    for (int ni = 0; ni < 4; ++ni) acc[mi][ni] = (f32x4){0.f, 0.f, 0.f, 0.f};

#define MF(dst, afrag, bfrag)                                                        \
  if constexpr (KIND == 2)                                                           \
    dst = __builtin_amdgcn_mfma_f32_16x16x32_bf16(afrag, bfrag, dst, 0, 0, 0);       \
  else                                                                               \
    dst = __builtin_amdgcn_mfma_f32_16x16x32_bf16(bfrag, afrag, dst, 0, 0, 0);

  stage_tile(0, 0);
  stage_tile(1, 1);
  asm volatile("s_waitcnt vmcnt(8)" ::: "memory");
  __builtin_amdgcn_s_barrier();
  asm volatile("" ::: "memory");

  bf16x8 a03[4][2], a47[4][2], b01[2][2], b23[2][2];
#pragma unroll
  for (int t = 0; t < 8; ++t) {
    int buf = t & 1;
    // ---- phase 0: A m0-3 + B n0-1 ----
#pragma unroll
    for (int mi = 0; mi < 4; ++mi) { a03[mi][0] = lda(buf, mi, 0); a03[mi][1] = lda(buf, mi, 1); }
#pragma unroll
    for (int ni = 0; ni < 2; ++ni) { b01[ni][0] = ldb(buf, ni, 0); b01[ni][1] = ldb(buf, ni, 1); }
    __builtin_amdgcn_s_setprio(1);
#pragma unroll
    for (int mi = 0; mi < 4; ++mi)
#pragma unroll
      for (int ni = 0; ni < 2; ++ni)
#pragma unroll
        for (int k = 0; k < 2; ++k) { MF(acc[mi][ni], a03[mi][k], b01[ni][k]); }
    __builtin_amdgcn_s_setprio(0);
    asm volatile("" ::: "memory");
    __builtin_amdgcn_s_barrier();
    asm volatile("" ::: "memory");
    // ---- phase 1: A m4-7 ----
#pragma unroll
    for (int mi = 0; mi < 4; ++mi) { a47[mi][0] = lda(buf, mi + 4, 0); a47[mi][1] = lda(buf, mi + 4, 1); }
    __builtin_amdgcn_s_setprio(1);
#pragma unroll
    for (int mi = 0; mi < 4; ++mi)
#pragma unroll
      for (int ni = 0; ni < 2; ++ni)
#pragma unroll
        for (int k = 0; k < 2; ++k) { MF(acc[mi + 4][ni], a47[mi][k], b01[ni][k]); }
    __builtin_amdgcn_s_setprio(0);
    asm volatile("" ::: "memory");
    __builtin_amdgcn_s_barrier();
    asm volatile("" ::: "memory");
    // ---- phase 2: B n2-3 ----
#pragma unroll
    for (int ni = 0; ni < 2; ++ni) { b23[ni][0] = ldb(buf, ni + 2, 0); b23[ni][1] = ldb(buf, ni + 2, 1); }
    __builtin_amdgcn_s_setprio(1);
#pragma unroll
    for (int mi = 0; mi < 4; ++mi)
#pragma unroll
      for (int ni = 0; ni < 2; ++ni)
#pragma unroll
        for (int k = 0; k < 2; ++k) { MF(acc[mi + 4][ni + 2], a47[mi][k], b23[ni][k]); }
    __builtin_amdgcn_s_setprio(0);
    asm volatile("" ::: "memory");
    __builtin_amdgcn_s_barrier();
    asm volatile("" ::: "memory");
    // ---- phase 3: stage t+2 ----
    if (t < 6) stage_tile(t + 2, buf);
    __builtin_amdgcn_s_setprio(1);
#pragma unroll
    for (int mi = 0; mi < 4; ++mi)
#pragma unroll
      for (int ni = 0; ni < 2; ++ni)
#pragma unroll
        for (int k = 0; k < 2; ++k) { MF(acc[mi][ni + 2], a03[mi][k], b23[ni][k]); }
    __builtin_amdgcn_s_setprio(0);
    if (t < 6)       asm volatile("s_waitcnt vmcnt(8)" ::: "memory");
    else if (t == 6) asm volatile("s_waitcnt vmcnt(0)" ::: "memory");
    asm volatile("" ::: "memory");
    __builtin_amdgcn_s_barrier();
    asm volatile("" ::: "memory");
  }
#undef MF

  // ---- epilogues (no LDS reuse, no barrier needed) ----
  if constexpr (KIND == 0) {
    // swapped: m = ...+lr, n = ...+lg*4+r (walks hd) -> packed 8B stores
    int z = n0 >> 9;
    int h = ((n0 + wn * 64) >> 6) & 7;
    unsigned short* outp = (z ? O1 : O0) + (size_t)(mt * 8 + h) * 16384;
#pragma unroll
    for (int ni = 0; ni < 4; ++ni) {
      int hd0 = ni * 16 + lg * 4;
#pragma unroll
      for (int mi = 0; mi < 8; ++mi) {
        int tq = wm * 128 + mi * 16 + lr;
        *(bf16x4*)&outp[(size_t)tq * 64 + hd0] = cvt4(acc[mi][ni]);
      }
    }
  } else if constexpr (KIND == 1) {
    // swapped: packed float4 + bias
#pragma unroll
    for (int ni = 0; ni < 4; ++ni) {
      int nb = n0 + wn * 64 + ni * 16 + lg * 4;
      float4 b4 = *(const float4*)&bo[nb];
#pragma unroll
      for (int mi = 0; mi < 8; ++mi) {
        int mg = m0 + wm * 128 + mi * 16 + lr;
        float4 o;
        o.x = acc[mi][ni][0] + b4.x; o.y = acc[mi][ni][1] + b4.y;
        o.z = acc[mi][ni][2] + b4.z; o.w = acc[mi][ni][3] + b4.w;
        *(float4*)&outf[(size_t)mg * 512 + nb] = o;
      }
    }
  } else {
    // normal: n = ...+lr (hd), m = ...+lg*4+r (walks t) -> packed V^T stores
    int h = (n0 >> 6) + wn;
    unsigned short* outp = O0 + (size_t)(mt * 8 + h) * 16384;
#pragma unroll
    for (int ni = 0; ni < 4; ++ni) {
      int hd = ni * 16 + lr;
#pragma unroll
      for (int mi = 0; mi < 8; ++mi) {
        int tq = wm * 128 + mi * 16 + lg * 4;
        *(bf16x4*)&outp[(size_t)hd * 256 + tq] = cvt4(acc[mi][ni]);
      }
    }
  }
}

// ---------------- fused causal attention v2: LDS K/V, balanced chunk pairs ----------------
// One 8-wave block per (b,h). K[256][64] + V^T[64][256] staged once via async16
// (xor-pre-swizzled source), each wave handles chunks {wid, 15-wid} = 17 tiles each.
// All K/V reads are LDS (12cyc) instead of L2 (200+cyc) -> kills the latency stall.
__global__ __launch_bounds__(512, 1) void k_attn2(
    const unsigned short* __restrict__ Qb,
    const unsigned short* __restrict__ Kb,
    const unsigned short* __restrict__ Vtb,
    unsigned short* __restrict__ Ob) {  // [B,T,512] bf16 (concat heads)
  __shared__ unsigned short Ks[16384];       // [256][64], chunk^=(row&7)
  __shared__ unsigned short Vs[16384];       // [64][256], chunk^=((row&7)<<2)
  __shared__ unsigned short Ps[8][16][264];  // per-wave P rows (264: 16B-aligned stride)
  int bh = blockIdx.x;
  int tid = threadIdx.x, wid = tid >> 6, lane = tid & 63, lr = lane & 15, lg = lane >> 4;
  int bb = bh >> 3, h = bh & 7;
  const unsigned short* Kg = Kb + (size_t)bh * 16384;
  const unsigned short* Vg = Vtb + (size_t)bh * 16384;
#pragma unroll
  for (int c = 0; c < 4; ++c) {
    int d = (wid * 4 + c) * 64 + lane;
    int kr = d >> 3, kc = (d & 7) ^ (kr & 7);
    async16(Kg + (size_t)kr * 64 + kc * 8, Ks + (wid * 4 + c) * 512);
    int vr = d >> 5, vc = (d & 31) ^ ((vr & 7) << 2);
    async16(Vg + (size_t)vr * 256 + vc * 8, Vs + (wid * 4 + c) * 512);
  }
  __syncthreads();   // vmcnt(0) drain + barrier

#pragma unroll
  for (int cc = 0; cc < 2; ++cc) {
    int ci = cc ? (15 - wid) : wid;
    int t0 = ci * 16, trow = t0 + lr;
    int ntV = ci + 1;
    int ntE = (ntV + 1) & ~1;
    int nk32 = ntE >> 1;
    const unsigned short* qsrc = Qb + (size_t)bh * 16384 + (size_t)(t0 + lr) * 64 + lg * 8;
    bf16x8 bq0 = *(const bf16x8*)qsrc;
    bf16x8 bq1 = *(const bf16x8*)(qsrc + 32);
    f32x4 acc[16];
#pragma unroll
    for (int nt = 0; nt < 16; ++nt)
      if (nt < ntE) acc[nt] = (f32x4){0.f, 0.f, 0.f, 0.f};
#pragma unroll
    for (int nt = 0; nt < 16; ++nt)
      if (nt < ntV) {
        int row = nt * 16 + lr;
        bf16x8 ak0 = *(const bf16x8*)&Ks[row * 64 + ((0 + lg) ^ (lr & 7)) * 8];
        acc[nt] = __builtin_amdgcn_mfma_f32_16x16x32_bf16(ak0, bq0, acc[nt], 0, 0, 0);
        bf16x8 ak1 = *(const bf16x8*)&Ks[row * 64 + ((4 + lg) ^ (lr & 7)) * 8];
        acc[nt] = __builtin_amdgcn_mfma_f32_16x16x32_bf16(ak1, bq1, acc[nt], 0, 0, 0);
      }
    // acc[nt][r] = S[t=trow][s=nt*16+lg*4+r]
    float m = -3.0e38f;
#pragma unroll
    for (int nt = 0; nt < 16; ++nt)
      if (nt < ntE) {
#pragma unroll
        for (int r = 0; r < 4; ++r) {
          float v = acc[nt][r] * 0.125f;
          if (nt * 16 + lg * 4 + r > trow) v = -1.0e30f;
          acc[nt][r] = v;
          m = fmaxf(m, v);
        }
      }
    m = fmaxf(m, __shfl_xor(m, 16));
    m = fmaxf(m, __shfl_xor(m, 32));
    float s = 0.f;
#pragma unroll
    for (int nt = 0; nt < 16; ++nt)
      if (nt < ntE) {
        bf16x4 pk;
#pragma unroll
        for (int r = 0; r < 4; ++r) {
          float p = __expf(acc[nt][r] - m);
          s += p;
          pk[r] = (__bf16)p;
        }
        *(bf16x4*)&Ps[wid][lr][nt * 16 + lg * 4] = pk;   // packed 8B
      }
    s += __shfl_xor(s, 16);
    s += __shfl_xor(s, 32);
    float inv = 1.0f / s;
    __threadfence_block();  // order P writes before same-wave P reads
    f32x4 aco[4];
#pragma unroll
    for (int vt = 0; vt < 4; ++vt) aco[vt] = (f32x4){0.f, 0.f, 0.f, 0.f};
#pragma unroll
    for (int k32 = 0; k32 < 8; ++k32)
      if (k32 < nk32) {
        bf16x8 pb = *(const bf16x8*)&Ps[wid][lr][k32 * 32 + lg * 8];
#pragma unroll
        for (int vt = 0; vt < 4; ++vt) {
          int row = vt * 16 + lr;
          bf16x8 av = *(const bf16x8*)&Vs[row * 256 + (((k32 * 4 + lg) ^ ((lr & 7) << 2)) * 8)];
          aco[vt] = __builtin_amdgcn_mfma_f32_16x16x32_bf16(av, pb, aco[vt], 0, 0, 0);
        }
      }
    // aco[vt][r] = O[t=trow][hd=vt*16+lg*4+r]
    unsigned short* obase = Ob + (size_t)(bb * 256 + trow) * 512 + h * 64 + lg * 4;
#pragma unroll
    for (int vt = 0; vt < 4; ++vt) {
      bf16x4 ov;
#pragma unroll
      for (int r = 0; r < 4; ++r) ov[r] = (__bf16)(aco[vt][r] * inv);
      *(bf16x4*)(obase + vt * 16) = ov;
    }
    __threadfence_block();  // PV reads done before next cc's P writes (WAR)
  }
}

extern "C" void kernel_launch(void* const* d_in, const int* in_sizes, int n_in,
                              void* d_out, int out_size, void* d_ws, size_t ws_size,
                              hipStream_t stream) {
  (void)in_sizes; (void)n_in; (void)out_size; (void)ws_size;
  const float* x = (const float*)d_in[0];
  const float* Wq = (const float*)d_in[1];
  const float* Wk = (const float*)d_in[2];
  const float* Wv = (const float*)d_in[3];
  const float* Wo = (const float*)d_in[4];
  const float* bo = (const float*)d_in[5];
  float* out = (float*)d_out;
  char* ws = (char*)d_ws;
  const size_t MB = 1024 * 1024;
  unsigned short* Qb = (unsigned short*)(ws);             // 32 MB
  unsigned short* Kb = (unsigned short*)(ws + 32 * MB);   // 32 MB
  unsigned short* Vtb = (unsigned short*)(ws + 64 * MB);  // 32 MB
  unsigned short* xb = (unsigned short*)(ws + 96 * MB);   // 32 MB (reused as attn out)
  unsigned short* Wqt = (unsigned short*)(ws + 128 * MB); // [512][512]; Wkt follows -> [1024][512]
  unsigned short* Wkt = Wqt + 262144;
  unsigned short* Wvt = Wkt + 262144;
  unsigned short* Wot = Wvt + 262144;

  hipLaunchKernelGGL(k_convert_x, dim3(8192), dim3(256), 0, stream, x, xb);
  hipLaunchKernelGGL(k_transpose_w, dim3(1, 8, 8), dim3(256), 0, stream, Wq, Wqt, 512, 64);
  hipLaunchKernelGGL(k_transpose_w, dim3(1, 8, 8), dim3(256), 0, stream, Wk, Wkt, 512, 64);
  hipLaunchKernelGGL(k_transpose_w, dim3(1, 8, 8), dim3(256), 0, stream, Wv, Wvt, 512, 64);
  hipLaunchKernelGGL(k_transpose_w, dim3(8, 8, 1), dim3(256), 0, stream, Wo, Wot, 512, 512);
  // QK projection: B = [Wqt;Wkt] = [1024][512]
  hipLaunchKernelGGL((k_gemmP<0>), dim3(512), dim3(512), 0, stream,
                     xb, Wqt, Qb, Kb, (const float*)nullptr, (float*)nullptr);
  // V projection -> V^T
  hipLaunchKernelGGL((k_gemmP<2>), dim3(256), dim3(512), 0, stream,
                     xb, Wvt, Vtb, (unsigned short*)nullptr, (const float*)nullptr, (float*)nullptr);
  hipLaunchKernelGGL(k_attn2, dim3(1024), dim3(512), 0, stream, Qb, Kb, Vtb, xb);
  hipLaunchKernelGGL((k_gemmP<1>), dim3(256), dim3(512), 0, stream,
                     xb, Wot, (unsigned short*)nullptr, (unsigned short*)nullptr, bo, out);
}